// Round 12
// baseline (439.356 us; speedup 1.0000x reference)
//
#include <hip/hip_runtime.h>

#define DD 128
#define NBC 64  // CSR edge chunks

typedef float v2f __attribute__((ext_vector_type(2)));

// ---------------- bf16 helpers (RTN-even) ----------------
__device__ __forceinline__ unsigned int rtn16(float f) {
  unsigned int u = __float_as_uint(f);
  return (u + 0x7FFFu + ((u >> 16) & 1u)) >> 16;
}
#define UNPK_LO(u) __uint_as_float((u) << 16)
#define UNPK_HI(u) __uint_as_float((u) & 0xFFFF0000u)

// ---------------- CSR build (atomic-free at global scope) ----------------

__global__ __launch_bounds__(256) void hist2_kernel(const int* __restrict__ src,
                                                    const int* __restrict__ dst,
                                                    unsigned int* __restrict__ hsrc,
                                                    unsigned int* __restrict__ hdst,
                                                    int e, int n, int ec) {
  __shared__ unsigned int h[32768];  // 128 KB: supports n <= 65536
  int c = blockIdx.x & (NBC - 1);
  bool is_src = blockIdx.x >= NBC;
  const int* __restrict__ ids = is_src ? src : dst;
  unsigned int* __restrict__ out = is_src ? hsrc : hdst;
  int nw = (n + 1) >> 1;
  for (int w = threadIdx.x; w < nw; w += 256) h[w] = 0u;
  __syncthreads();
  int lo = c * ec;
  int hi = lo + ec; if (hi > e) hi = e;
  for (int i = lo + threadIdx.x; i < hi; i += 256) {
    int d = ids[i];
    atomicAdd(&h[d >> 1], (d & 1) ? 0x10000u : 1u);
  }
  __syncthreads();
  for (int w = threadIdx.x; w < nw; w += 256) out[(size_t)c * nw + w] = h[w];
}

// Merged: reduce hists -> deg/norms, in-place chunk-exclusive-prefix of hdst,
// AND per-block (512-node) degree sums -> bsum (feeds the scan directly).
__global__ __launch_bounds__(256) void degnorm_prefix_kernel(
    const unsigned int* __restrict__ hsrc, unsigned int* __restrict__ hdst,
    int* __restrict__ deg_in, float* __restrict__ norm_src,
    float* __restrict__ norm_dst, int* __restrict__ bsum, int n) {
  __shared__ int ws[4];
  int nw = (n + 1) >> 1;
  int tid = threadIdx.x, lane = tid & 63, wid = tid >> 6;
  int w = blockIdx.x * 256 + tid;
  unsigned int slo = 0, shi = 0, dlo = 0, dhi = 0;
  if (w < nw) {
    for (int c = 0; c < NBC; ++c) {
      unsigned int a = hsrc[(size_t)c * nw + w];
      slo += a & 0xFFFFu; shi += a >> 16;
      size_t idx = (size_t)c * nw + w;
      unsigned int v = hdst[idx];
      hdst[idx] = dlo | (dhi << 16);  // exclusive prefix over chunks
      dlo += v & 0xFFFFu; dhi += v >> 16;
    }
    int n0 = 2 * w, n1 = 2 * w + 1;
    deg_in[n0] = (int)dlo;
    norm_src[n0] = 1.0f / sqrtf((float)(slo < 1u ? 1u : slo));
    norm_dst[n0] = 1.0f / sqrtf((float)(dlo < 1u ? 1u : dlo));
    if (n1 < n) {
      deg_in[n1] = (int)dhi;
      norm_src[n1] = 1.0f / sqrtf((float)(shi < 1u ? 1u : shi));
      norm_dst[n1] = 1.0f / sqrtf((float)(dhi < 1u ? 1u : dhi));
    } else {
      dhi = 0;
    }
  }
  int s = (int)(dlo + dhi);
#pragma unroll
  for (int d = 32; d; d >>= 1) s += __shfl_xor(s, d, 64);
  if (lane == 0) ws[wid] = s;
  __syncthreads();
  if (tid == 0) bsum[blockIdx.x] = ws[0] + ws[1] + ws[2] + ws[3];
}

// Exclusive scan of block sums (single wave).
__global__ __launch_bounds__(64) void scan_bsum_kernel(int* __restrict__ bsum, int nb) {
  int lane = threadIdx.x;
  int run = 0;
  for (int base = 0; base < nb; base += 64) {
    int id = base + lane;
    int v = (id < nb) ? bsum[id] : 0;
    int sc = v;
#pragma unroll
    for (int d = 1; d < 64; d <<= 1) {
      int t = __shfl_up(sc, d, 64);
      if (lane >= d) sc += t;
    }
    if (id < nb) bsum[id] = run + sc - v;
    run += __shfl(sc, 63, 64);
  }
}

// Final scatter: 512 nodes per block (matches degnorm blocks), 2 nodes/thread.
__global__ __launch_bounds__(256) void scan_final_kernel(const int* __restrict__ cnt,
                                                         const int* __restrict__ bsum,
                                                         int* __restrict__ row_ptr,
                                                         int n, int e_total) {
  __shared__ int ws[4];
  int tid = threadIdx.x, lane = tid & 63, wid = tid >> 6;
  int id0 = blockIdx.x * 512 + tid * 2;
  int v0 = (id0 < n) ? cnt[id0] : 0;
  int v1 = (id0 + 1 < n) ? cnt[id0 + 1] : 0;
  int s = v0 + v1;
  int sc = s;
#pragma unroll
  for (int d = 1; d < 64; d <<= 1) {
    int t = __shfl_up(sc, d, 64);
    if (lane >= d) sc += t;
  }
  if (lane == 63) ws[wid] = sc;
  __syncthreads();
  int woff = 0;
  for (int w2 = 0; w2 < wid; ++w2) woff += ws[w2];
  int off = bsum[blockIdx.x] + woff + (sc - s);
  if (id0 < n) row_ptr[id0] = off;
  if (id0 + 1 < n) row_ptr[id0 + 1] = off + v0;
  if (blockIdx.x == 0 && tid == 0) row_ptr[n] = e_total;
}

// Fill adj: rank via LDS packed atomic; position = row_ptr[d] + chunk-prefix + rank.
__global__ __launch_bounds__(256) void fillx_kernel(const int* __restrict__ src,
                                                    const int* __restrict__ dst,
                                                    const unsigned int* __restrict__ hdst,
                                                    const int* __restrict__ row_ptr,
                                                    int* __restrict__ adj,
                                                    int e, int n, int ec) {
  __shared__ unsigned int h[32768];
  int c = blockIdx.x;
  int nw = (n + 1) >> 1;
  for (int w = threadIdx.x; w < nw; w += 256) h[w] = 0u;
  __syncthreads();
  int lo = c * ec;
  int hi = lo + ec; if (hi > e) hi = e;
  for (int i = lo + threadIdx.x; i < hi; i += 256) {
    int s = src[i];
    int d = dst[i];
    unsigned int old = atomicAdd(&h[d >> 1], (d & 1) ? 0x10000u : 1u);
    unsigned int rank = (d & 1) ? (old >> 16) : (old & 0xFFFFu);
    unsigned int pre = hdst[(size_t)c * nw + (d >> 1)];
    pre = (d & 1) ? (pre >> 16) : (pre & 0xFFFFu);
    adj[row_ptr[d] + (int)pre + (int)rank] = s;
  }
}

// g[i,:] = bf16(feat[i,:] * norm_src[i]); row n of BOTH buffers = zeros.
__global__ __launch_bounds__(256) void prescale_kernel(const float* __restrict__ feat,
                                                       const float* __restrict__ ns,
                                                       unsigned short* __restrict__ ga,
                                                       unsigned short* __restrict__ gb,
                                                       int n) {
  int i = blockIdx.x * 256 + threadIdx.x;  // uint2 (8-bf16) index
  if (i >= (n + 1) * 32) return;
  if (i >= n * 32) {  // zero row
    ((uint2*)ga)[i] = make_uint2(0u, 0u);
    ((uint2*)gb)[i] = make_uint2(0u, 0u);
    return;
  }
  float4 v = ((const float4*)feat)[i];
  float s = ns[i >> 5];
  unsigned int p0 = rtn16(v.x * s), p1 = rtn16(v.y * s);
  unsigned int p2 = rtn16(v.z * s), p3 = rtn16(v.w * s);
  ((uint2*)ga)[i] = make_uint2(p0 | (p1 << 16), p2 | (p3 << 16));
}

// ---------------- fused layer: agg (bf16 gather-sum) + f32 gemm + relu -------
// Round-9 gather structure (32 VGPR, 4 loads in flight, uniform 16-edge loop
// with zero-row pad) + packed-f32 (v_pk_add/v_pk_fma) accumulate and gemm.
__global__ __launch_bounds__(256) void layer_kernel(const unsigned short* __restrict__ gin,
                                                    unsigned short* __restrict__ goutb,
                                                    float* __restrict__ goutf,
                                                    const int* __restrict__ adj,
                                                    const int* __restrict__ row_ptr,
                                                    const float* __restrict__ ns,
                                                    const float* __restrict__ ndv,
                                                    const float* __restrict__ W,
                                                    const float* __restrict__ bias,
                                                    int n, int last) {
  __shared__ float Xs[32][DD];
  int tid = threadIdx.x;
  int lane = tid & 63;
  int wv = tid >> 6;
  int m4 = lane & 15;   // 16B chunk of the 256B row
  int q = lane >> 4;    // quarter: which of 4 concurrent edges
  int row0 = blockIdx.x * 32;
  const uint4* g4 = (const uint4*)gin;

  for (int r = wv; r < 32; r += 4) {
    int node = row0 + r;
    v2f a0 = {0.f, 0.f}, a1 = {0.f, 0.f}, a2 = {0.f, 0.f}, a3 = {0.f, 0.f};
    float scale = 0.f;
#define ACC8(v)                                           \
  a0 += (v2f){UNPK_LO(v.x), UNPK_HI(v.x)};                \
  a1 += (v2f){UNPK_LO(v.y), UNPK_HI(v.y)};                \
  a2 += (v2f){UNPK_LO(v.z), UNPK_HI(v.z)};                \
  a3 += (v2f){UNPK_LO(v.w), UNPK_HI(v.w)};
    if (node < n) {
      scale = ndv[node];
      int beg = row_ptr[node];
      int end = row_ptr[node + 1];
      for (int j = beg; j < end; j += 16) {  // uniform: 4 row-loads in flight
        int i0 = j + q;
        int i1 = j + 4 + q;
        int i2 = j + 8 + q;
        int i3 = j + 12 + q;
        int e0 = (i0 < end) ? adj[i0] : n;
        int e1 = (i1 < end) ? adj[i1] : n;
        int e2 = (i2 < end) ? adj[i2] : n;
        int e3 = (i3 < end) ? adj[i3] : n;
        uint4 v0 = g4[(size_t)e0 * 16 + m4];
        uint4 v1 = g4[(size_t)e1 * 16 + m4];
        uint4 v2 = g4[(size_t)e2 * 16 + m4];
        uint4 v3 = g4[(size_t)e3 * 16 + m4];
        ACC8(v0); ACC8(v1); ACC8(v2); ACC8(v3);
      }
    }
#undef ACC8
    // sum quarters: lanes {m4, m4+16, m4+32, m4+48}
    a0.x += __shfl_xor(a0.x, 16, 64); a0.x += __shfl_xor(a0.x, 32, 64);
    a0.y += __shfl_xor(a0.y, 16, 64); a0.y += __shfl_xor(a0.y, 32, 64);
    a1.x += __shfl_xor(a1.x, 16, 64); a1.x += __shfl_xor(a1.x, 32, 64);
    a1.y += __shfl_xor(a1.y, 16, 64); a1.y += __shfl_xor(a1.y, 32, 64);
    a2.x += __shfl_xor(a2.x, 16, 64); a2.x += __shfl_xor(a2.x, 32, 64);
    a2.y += __shfl_xor(a2.y, 16, 64); a2.y += __shfl_xor(a2.y, 32, 64);
    a3.x += __shfl_xor(a3.x, 16, 64); a3.x += __shfl_xor(a3.x, 32, 64);
    a3.y += __shfl_xor(a3.y, 16, 64); a3.y += __shfl_xor(a3.y, 32, 64);
    if (q == 0) {
      float* xp = &Xs[r][m4 * 8];
      xp[0] = a0.x * scale; xp[1] = a0.y * scale;
      xp[2] = a1.x * scale; xp[3] = a1.y * scale;
      xp[4] = a2.x * scale; xp[5] = a2.y * scale;
      xp[6] = a3.x * scale; xp[7] = a3.y * scale;
    }
  }
  __syncthreads();

  int tx = tid & 31;   // col group: cols tx*4..tx*4+3 (pairs jp=0: +0,+1; jp=1: +2,+3)
  int ty = tid >> 5;   // row group: rows ty*4..ty*4+3
  v2f acc[4][2] = {};
  const float4* wp0 = (const float4*)W + tx;
  for (int k4 = 0; k4 < DD / 4; ++k4) {
    const float4* wp = wp0 + (size_t)k4 * 4 * 32;
    float4 w0 = wp[0];
    float4 w1 = wp[32];
    float4 w2 = wp[64];
    float4 w3 = wp[96];
    v2f w0a = {w0.x, w0.y}, w0b = {w0.z, w0.w};
    v2f w1a = {w1.x, w1.y}, w1b = {w1.z, w1.w};
    v2f w2a = {w2.x, w2.y}, w2b = {w2.z, w2.w};
    v2f w3a = {w3.x, w3.y}, w3b = {w3.z, w3.w};
#pragma unroll
    for (int i = 0; i < 4; ++i) {
      float4 x = *(const float4*)&Xs[ty * 4 + i][k4 * 4];
      acc[i][0] += x.x * w0a; acc[i][1] += x.x * w0b;
      acc[i][0] += x.y * w1a; acc[i][1] += x.y * w1b;
      acc[i][0] += x.z * w2a; acc[i][1] += x.z * w2b;
      acc[i][0] += x.w * w3a; acc[i][1] += x.w * w3b;
    }
  }
  float4 bv = *(const float4*)(bias + tx * 4);
#pragma unroll
  for (int i = 0; i < 4; ++i) {
    int r = row0 + ty * 4 + i;
    if (r < n) {
      float4 o;
      o.x = fmaxf(acc[i][0].x + bv.x, 0.f);
      o.y = fmaxf(acc[i][0].y + bv.y, 0.f);
      o.z = fmaxf(acc[i][1].x + bv.z, 0.f);
      o.w = fmaxf(acc[i][1].y + bv.w, 0.f);
      if (last) {
        *(float4*)(goutf + (size_t)r * DD + tx * 4) = o;
      } else {
        float s = ns[r];
        unsigned int p0 = rtn16(o.x * s), p1 = rtn16(o.y * s);
        unsigned int p2 = rtn16(o.z * s), p3 = rtn16(o.w * s);
        ((uint2*)(goutb + (size_t)r * DD))[tx] =
            make_uint2(p0 | (p1 << 16), p2 | (p3 << 16));
      }
    }
  }
}

// ---------------- launch ----------------

extern "C" void kernel_launch(void* const* d_in, const int* in_sizes, int n_in,
                              void* d_out, int out_size, void* d_ws, size_t ws_size,
                              hipStream_t stream) {
  const float* feat = (const float*)d_in[0];
  const int* src = (const int*)d_in[1];
  const int* dst = (const int*)d_in[2];
  const float* W = (const float*)d_in[3];
  const float* b = (const float*)d_in[4];
  const int N = in_sizes[0] / DD;
  const int E = in_sizes[1];
  const int L = in_sizes[3] / (DD * DD);
  const int NW = (N + 1) >> 1;
  const int EC = (E + NBC - 1) / NBC;

  char* p = (char*)d_ws;
  auto alloc = [&](size_t bytes) {
    void* r = (void*)p;
    p += (bytes + 255) & ~(size_t)255;
    return r;
  };
  int* deg_in = (int*)alloc((size_t)N * 4);
  int* row_ptr = (int*)alloc(((size_t)N + 1) * 4);
  int* adj = (int*)alloc((size_t)E * 4);
  float* norm_src = (float*)alloc((size_t)N * 4);
  float* norm_dst = (float*)alloc((size_t)N * 4);
  int* bsum = (int*)alloc(((size_t)N / 512 + 2) * 4);
  unsigned int* hsrc = (unsigned int*)alloc((size_t)NBC * NW * 4);
  unsigned int* hdst = (unsigned int*)alloc((size_t)NBC * NW * 4);
  unsigned short* ga = (unsigned short*)alloc(((size_t)N + 1) * DD * 2);
  unsigned short* gb = (unsigned short*)alloc(((size_t)N + 1) * DD * 2);

  const int nwb = (NW + 255) / 256;  // == ceil(N/512): shared by degnorm & scan

  hist2_kernel<<<2 * NBC, 256, 0, stream>>>(src, dst, hsrc, hdst, E, N, EC);
  degnorm_prefix_kernel<<<nwb, 256, 0, stream>>>(hsrc, hdst, deg_in, norm_src,
                                                 norm_dst, bsum, N);
  scan_bsum_kernel<<<1, 64, 0, stream>>>(bsum, nwb);
  scan_final_kernel<<<nwb, 256, 0, stream>>>(deg_in, bsum, row_ptr, N, E);
  fillx_kernel<<<NBC, 256, 0, stream>>>(src, dst, hdst, row_ptr, adj, E, N, EC);

  float* out_f = (float*)d_out;
  prescale_kernel<<<((N + 1) * 32 + 255) / 256, 256, 0, stream>>>(feat, norm_src,
                                                                  ga, gb, N);
  for (int l = 0; l < L; ++l) {
    const unsigned short* gi = (l & 1) ? gb : ga;
    unsigned short* go = (l & 1) ? ga : gb;
    int last = (l == L - 1) ? 1 : 0;
    layer_kernel<<<(N + 31) / 32, 256, 0, stream>>>(
        gi, go, out_f, adj, row_ptr, norm_src, norm_dst,
        W + (size_t)l * DD * DD, b + (size_t)l * DD, N, last);
  }
}